// Round 3
// baseline (299.582 us; speedup 1.0000x reference)
//
#include <hip/hip_runtime.h>
#include <hip/hip_bf16.h>
#include <math.h>

// Sizes (fixed by the problem)
#define BATCH 16
#define TLEN  512
#define HD    16     // per-direction hidden
#define HID   32     // 2*HD

// Static device scratch — avoids any assumption about ws_size.
// All arrays are fully written before being read on every call.
__device__ float g_outBT[BATCH * TLEN * HID];   // 1 MB
__device__ float g_preA [BATCH * TLEN * HID];   // 1 MB
__device__ float g_Ct   [BATCH * HID * TLEN];   // 1 MB
__device__ float g_un   [BATCH * TLEN];
__device__ float g_w2d  [BATCH * TLEN];
__device__ float g_prob [BATCH * TLEN];

__device__ __forceinline__ float sigm_(float x) {
    return 1.0f / (1.0f + __expf(-x));
}
__device__ __forceinline__ float tanh_(float x) {
    // safe form: large +x -> 1, large -x -> -1
    float e = __expf(2.0f * x);
    return 1.0f - 2.0f / (e + 1.0f);
}

// ---------------------------------------------------------------------------
// K1: bidirectional LSTM. One block (64 thr = 1 wave) per (dir, batch).
// Lane = gate index g in [0,64). Gate order (torch): i, f, g, o (16 each).
// Hidden state replicated in registers across all lanes; distribution via
// shuffles (wave-synchronous, no LDS, no barriers in the loop).
// Writes outBT[b][t][32]  (fwd -> [0:16), bwd -> [16:32)).
// ---------------------------------------------------------------------------
__global__ __launch_bounds__(64) void k1_lstm(
    const float* __restrict__ sent,   // [B,T]
    const float* __restrict__ h0,     // [2,B,16]
    const float* __restrict__ c0,     // [2,B,16]
    const float* __restrict__ Wih_f, const float* __restrict__ Whh_f, const float* __restrict__ b_f,
    const float* __restrict__ Wih_b, const float* __restrict__ Whh_b, const float* __restrict__ b_b)
{
    const int blk  = blockIdx.x;      // 0..31
    const int dir  = blk >> 4;        // 0 fwd, 1 bwd
    const int b    = blk & 15;
    const int lane = threadIdx.x;     // gate index
    const int hl   = lane & 15;       // hidden unit this lane's quad handles

    const float* Wih  = dir ? Wih_b : Wih_f;
    const float* Whh  = dir ? Whh_b : Whh_f;
    const float* bias = dir ? b_b   : b_f;

    // per-lane weights
    float w[16];
    #pragma unroll
    for (int k = 0; k < 16; ++k) w[k] = Whh[lane * 16 + k];
    const float wx = Wih[lane];
    const float bg = bias[lane];

    // replicated hidden state (all lanes hold full h), per-lane c for unit hl
    float hr[16];
    #pragma unroll
    for (int k = 0; k < 16; ++k) hr[k] = h0[dir * (BATCH * HD) + b * HD + k];
    float c = c0[dir * (BATCH * HD) + b * HD + hl];

    const float* srow = sent + b * TLEN;
    float* obase = g_outBT + (size_t)b * TLEN * HID + dir * HD;

    for (int t = 0; t < TLEN; ++t) {
        const int ti = dir ? (TLEN - 1 - t) : t;
        const float x = srow[ti];

        // gate pre-activation for this lane's gate: x*wx + b + Whh_row . h
        float d0 = fmaf(w[0],  hr[0],  fmaf(w[1],  hr[1],  fmaf(w[2],  hr[2],  w[3]  * hr[3])));
        float d1 = fmaf(w[4],  hr[4],  fmaf(w[5],  hr[5],  fmaf(w[6],  hr[6],  w[7]  * hr[7])));
        float d2 = fmaf(w[8],  hr[8],  fmaf(w[9],  hr[9],  fmaf(w[10], hr[10], w[11] * hr[11])));
        float d3 = fmaf(w[12], hr[12], fmaf(w[13], hr[13], fmaf(w[14], hr[14], w[15] * hr[15])));
        float pre = fmaf(x, wx, bg) + ((d0 + d1) + (d2 + d3));

        // gather the 4 gates for hidden unit hl (all lanes do this redundantly)
        float gi = __shfl(pre, hl);
        float gf = __shfl(pre, hl + 16);
        float gg = __shfl(pre, hl + 32);
        float go = __shfl(pre, hl + 48);

        float si = sigm_(gi), sf = sigm_(gf), so = sigm_(go);
        float tg = tanh_(gg);
        c = fmaf(sf, c, si * tg);
        float hn = so * tanh_(c);

        // rebroadcast the new hidden state to all lanes (lane k holds unit k&15)
        #pragma unroll
        for (int k = 0; k < 16; ++k) hr[k] = __shfl(hn, k);

        if (lane < 16) obase[(size_t)ti * HID + lane] = hn;
    }
}

// ---------------------------------------------------------------------------
// K2: projections. Thread per (b,t). W1 etc. staged in LDS.
//   preA[b][t][h] = out[b,t,:] . W1[h,0:32]  + b1[h]
//   Ct  [b][h][t] = out[b,t,:] . W1[h,32:64]           (transposed for K3)
//   un  [b][t]    = out . Wu + bu
//   w2d [b][t]    = out . Wout
// ---------------------------------------------------------------------------
__global__ __launch_bounds__(256) void k2_proj(
    const float* __restrict__ W1,     // [32,64]
    const float* __restrict__ b1,     // [32]
    const float* __restrict__ Wu,     // [32] (row 0 of [1,32])
    const float* __restrict__ bu,     // [1]
    const float* __restrict__ Wout)   // [32]
{
    __shared__ float w1s[HID * 64];   // 32x64
    __shared__ float b1s[HID], wus[HID], wos[HID];
    const int tid = threadIdx.x;
    for (int k = tid; k < HID * 64; k += 256) w1s[k] = W1[k];
    if (tid < HID) { b1s[tid] = b1[tid]; wus[tid] = Wu[tid]; wos[tid] = Wout[tid]; }
    __syncthreads();

    const int g = blockIdx.x * 256 + tid;    // 0..8191
    const int b = g >> 9;
    const int t = g & (TLEN - 1);

    // load this (b,t)'s 32-vector
    float o[32];
    const float4* src = (const float4*)(g_outBT + (size_t)g * HID);
    #pragma unroll
    for (int q = 0; q < 8; ++q) {
        float4 v = src[q];
        o[q * 4 + 0] = v.x; o[q * 4 + 1] = v.y; o[q * 4 + 2] = v.z; o[q * 4 + 3] = v.w;
    }

    float* pa = g_preA + (size_t)g * HID;
    float* ct = g_Ct + (size_t)b * HID * TLEN + t;
    #pragma unroll 4
    for (int h = 0; h < HID; ++h) {
        float a = b1s[h], cacc = 0.f;
        const float* wr = &w1s[h * 64];
        #pragma unroll
        for (int k = 0; k < HID; ++k) {
            a    = fmaf(o[k], wr[k], a);
            cacc = fmaf(o[k], wr[32 + k], cacc);
        }
        pa[h] = a;
        ct[(size_t)h * TLEN] = cacc;
    }

    float ua = 0.f, wa = 0.f;
    #pragma unroll
    for (int k = 0; k < HID; ++k) { ua = fmaf(o[k], wus[k], ua); wa = fmaf(o[k], wos[k], wa); }
    g_un[g]  = ua + bu[0];
    g_w2d[g] = wa;
}

// ---------------------------------------------------------------------------
// K3: S[b,i] = sum_j sum_h relu(preA[b,i,h] + Ct[b,h,j]) * W2[h]
//     prob[b,i] = sigmoid((S - diag_i + (T-1)*b2)/100 + un[b,i])
// Block = (b, tile of 8 i's); 256 threads over j (each does j, j+256).
// ---------------------------------------------------------------------------
__global__ __launch_bounds__(256) void k3_binary(
    const float* __restrict__ W2,     // [32]
    const float* __restrict__ b2p)    // [1]
{
    const int b     = blockIdx.x >> 6;        // 16
    const int itile = blockIdx.x & 63;        // 64 tiles
    const int i0    = itile * 8;
    const int tid   = threadIdx.x;

    __shared__ float pa[8][HID];
    __shared__ float w2s[HID];
    __shared__ float redw[4][8];

    pa[tid >> 5][tid & 31] = g_preA[((size_t)b * TLEN + i0 + (tid >> 5)) * HID + (tid & 31)];
    if (tid < HID) w2s[tid] = W2[tid];
    __syncthreads();

    const float* ctb = g_Ct + (size_t)b * HID * TLEN;
    const int j0 = tid, j1 = tid + 256;

    float acc[8];
    #pragma unroll
    for (int ii = 0; ii < 8; ++ii) acc[ii] = 0.f;

    for (int h = 0; h < HID; ++h) {
        const float c0v = ctb[(size_t)h * TLEN + j0];
        const float c1v = ctb[(size_t)h * TLEN + j1];
        const float w   = w2s[h];
        #pragma unroll
        for (int ii = 0; ii < 8; ++ii) {
            const float p = pa[ii][h];
            acc[ii] = fmaf(fmaxf(p + c0v, 0.f), w, acc[ii]);
            acc[ii] = fmaf(fmaxf(p + c1v, 0.f), w, acc[ii]);
        }
    }

    // reduce 256 threads -> 8 sums
    #pragma unroll
    for (int ii = 0; ii < 8; ++ii) {
        float v = acc[ii];
        #pragma unroll
        for (int off = 32; off >= 1; off >>= 1) v += __shfl_down(v, off);
        if ((tid & 63) == 0) redw[tid >> 6][ii] = v;
    }
    __syncthreads();

    if (tid < 8) {
        const float S = redw[0][tid] + redw[1][tid] + redw[2][tid] + redw[3][tid];
        const int i = i0 + tid;
        float diag = 0.f;
        #pragma unroll
        for (int h = 0; h < HID; ++h)
            diag = fmaf(fmaxf(pa[tid][h] + ctb[(size_t)h * TLEN + i], 0.f), w2s[h], diag);
        const float b2 = b2p[0];
        const float s = (S - diag + (float)(TLEN - 1) * b2) * 0.01f + g_un[(size_t)b * TLEN + i];
        g_prob[(size_t)b * TLEN + i] = sigm_(s);
    }
}

// ---------------------------------------------------------------------------
// K4: out[b] = (1/T) * sum_t prob[b,t]*w2d[b,t] + bout
// ---------------------------------------------------------------------------
__global__ __launch_bounds__(64) void k4_pool(
    const float* __restrict__ boutp,
    float* __restrict__ out)
{
    const int b = blockIdx.x;
    const int tid = threadIdx.x;
    float acc = 0.f;
    for (int t = tid; t < TLEN; t += 64)
        acc = fmaf(g_prob[(size_t)b * TLEN + t], g_w2d[(size_t)b * TLEN + t], acc);
    #pragma unroll
    for (int off = 32; off >= 1; off >>= 1) acc += __shfl_down(acc, off);
    if (tid == 0) out[b] = acc * (1.0f / (float)TLEN) + boutp[0];
}

extern "C" void kernel_launch(void* const* d_in, const int* in_sizes, int n_in,
                              void* d_out, int out_size, void* d_ws, size_t ws_size,
                              hipStream_t stream) {
    const float* sent  = (const float*)d_in[0];
    const float* h0    = (const float*)d_in[1];
    const float* c0    = (const float*)d_in[2];
    const float* Wih_f = (const float*)d_in[3];
    const float* Whh_f = (const float*)d_in[4];
    const float* b_f   = (const float*)d_in[5];
    const float* Wih_b = (const float*)d_in[6];
    const float* Whh_b = (const float*)d_in[7];
    const float* b_b   = (const float*)d_in[8];
    const float* W1    = (const float*)d_in[9];
    const float* b1    = (const float*)d_in[10];
    const float* W2    = (const float*)d_in[11];
    const float* b2    = (const float*)d_in[12];
    const float* Wu    = (const float*)d_in[13];
    const float* bu    = (const float*)d_in[14];
    const float* Wout  = (const float*)d_in[15];
    const float* bout  = (const float*)d_in[16];

    k1_lstm<<<32, 64, 0, stream>>>(sent, h0, c0, Wih_f, Whh_f, b_f,
                                   Wih_b, Whh_b, b_b);
    k2_proj<<<32, 256, 0, stream>>>(W1, b1, Wu, bu, Wout);
    k3_binary<<<1024, 256, 0, stream>>>(W2, b2);
    k4_pool<<<16, 64, 0, stream>>>(bout, (float*)d_out);
}